// Round 3
// baseline (28400.589 us; speedup 1.0000x reference)
//
#include <hip/hip_runtime.h>
#include <stdint.h>

#define BATCH 256
#define SEQT  512
#define HID   1024
#define NCLS  128

using bf16x8 = __attribute__((ext_vector_type(8))) short;   // 8 bf16 (4 VGPRs)
using f32x4  = __attribute__((ext_vector_type(4))) float;
using i32x4  = __attribute__((ext_vector_type(4))) int;
using f32x4v = __attribute__((ext_vector_type(4))) float;

__device__ __forceinline__ unsigned short f2bf(float x) {
    unsigned u = __float_as_uint(x);
    u = u + 0x7FFFu + ((u >> 16) & 1u);          // round-to-nearest-even
    return (unsigned short)(u >> 16);
}
__device__ __forceinline__ float bf2f(unsigned short s) {
    return __uint_as_float(((unsigned)s) << 16);
}
__device__ __forceinline__ float sigf(float x) { return 1.f / (1.f + __expf(-x)); }
__device__ __forceinline__ float tanhf_(float x) {
    x = fminf(12.f, fmaxf(-12.f, x));
    float e = __expf(2.f * x);
    return (e - 1.f) / (e + 1.f);
}

// x[256][512] -> xT[512][256] so per-step index loads are contiguous int4
__global__ void xtrans_kernel(const int* __restrict__ x, int* __restrict__ xT) {
    int b = blockIdx.x;
    for (int t = threadIdx.x; t < SEQT; t += 256) xT[t * BATCH + b] = x[b * SEQT + t];
}

// Persistent LSTM. Grid = 256 blocks x 256 threads. REGULAR launch.
// Co-residency by CAPACITY: LDS 76KB (<=80KB) and <=256 VGPR => 2 blocks/CU
// capacity => all 256 blocks resident under ANY placement (even 128 live CUs).
// Block(bid): rg=bid&3 -> 64 batch rows; cg swizzled so each XCD's blocks share
// one A-panel in its L2. Cols = 64 (g|i|f|o x 16 hu).
// B-slice split: K-halves (k&255)<128 live in REGISTERS (16 frags/lane, loaded
// once via LDS bounce); (k&255)>=128 live in LDS (64KB, XOR-swizzled).
// 4 waves K-split (256 each); partial-C exchange via 12KB LDS in 2 phases.
__global__ void __launch_bounds__(256, 2) lstm_pers(
    const int* __restrict__ xT,
    const float* __restrict__ Wxg, const float* __restrict__ Whg, const float* __restrict__ b_g,
    const float* __restrict__ Wxi, const float* __restrict__ Whi, const float* __restrict__ b_i,
    const float* __restrict__ Wxf, const float* __restrict__ Whf, const float* __restrict__ b_f,
    const float* __restrict__ Wxo, const float* __restrict__ Who, const float* __restrict__ b_o,
    unsigned short* __restrict__ hbuf, unsigned int* __restrict__ flags)
{
    extern __shared__ char lds[];
    const int tid = threadIdx.x;
    const int bid = blockIdx.x;
    const int w   = tid >> 6;       // wave 0..3: owns K-quarter w and output rows [16w,16w+16)
    const int l   = tid & 63;
    const int rg  = bid & 3;                                   // XCD-local A panel
    const int cg  = ((bid >> 3) << 1) | ((bid >> 2) & 1);      // hidden-unit group 0..63
    const int r0  = rg * 64;
    const int hu0 = cg * 16;
    const int lHi = l >> 4;         // 0..3
    const int lLo = l & 15;

    // ---- one-time B staging. pass p stages k with (k&255) in [128p,128p+128):
    //   kl in [0,512), k = (kl>>7)*256 + 128p + (kl&127)
    //   LDS byte = c*1024 + ((2*kl) ^ ((c&7)<<4))   (c = gate*16 + col)
    // p=0 -> bounced into B0 registers; p=1 -> persistent LDS (B1).
    bf16x8 B0[4][4];                // [kk][gate], kk = K-sub 0..3 of my quarter
    {
        const int j4 = (tid & 3) * 4;
        const int g  = (tid >> 2) & 3;
        const int kq = tid >> 4;                      // 0..15, 32 kl each
        const float* Wsrc = (g == 0) ? Whg : (g == 1) ? Whi : (g == 2) ? Whf : Who;
        for (int p = 0; p < 2; ++p) {
            for (int kl = kq * 32; kl < kq * 32 + 32; ++kl) {
                int k = ((kl >> 7) << 8) + (p << 7) + (kl & 127);
                f32x4v v = *(const f32x4v*)(Wsrc + (size_t)k * HID + hu0 + j4);
#pragma unroll
                for (int e = 0; e < 4; ++e) {
                    int c = g * 16 + j4 + e;
                    *(unsigned short*)(lds + c * 1024 + ((2 * kl) ^ ((c & 7) << 4))) = f2bf(v[e]);
                }
            }
            __syncthreads();
            if (p == 0) {
#pragma unroll
                for (int kk = 0; kk < 4; ++kk)
#pragma unroll
                    for (int g2 = 0; g2 < 4; ++g2) {
                        int c  = g2 * 16 + lLo;
                        int kl = w * 128 + kk * 32 + lHi * 8;
                        B0[kk][g2] = *(const bf16x8*)(lds + c * 1024 + ((2 * kl) ^ ((c & 7) << 4)));
                    }
                __syncthreads();   // before pass 1 overwrites the region
            }
        }
    }

    const int hu = hu0 + lLo;
    const float vbg = b_g[hu], vbi = b_i[hu], vbf = b_f[hu], vbo = b_o[hu];

    int bbase[4];
#pragma unroll
    for (int g = 0; g < 4; ++g) bbase[g] = (g * 16 + lLo) * 1024;
    const int bmask = (lLo & 7) << 4;

    char* pb = lds + 65536;                 // 12KB exchange buffer (2-phase)
    float cst[4] = {0.f, 0.f, 0.f, 0.f};    // c-state: 4 rows x 1 hu per lane
    bool bailed = false;

    for (int t = 0; t < SEQT; ++t) {
        const unsigned short* cur = hbuf + (size_t)(t & 1) * BATCH * HID;
        unsigned short*       nxt = hbuf + (size_t)((t + 1) & 1) * BATCH * HID;

        // one-hot input projections for my 16 owned rows
        i32x4 idx = *(const i32x4*)(xT + t * BATCH + r0 + w * 16 + (lHi << 2));
        float xw0[4], xw1[4], xw2[4], xw3[4];
#pragma unroll
        for (int r = 0; r < 4; ++r) {
            xw0[r] = Wxg[(size_t)idx[r] * HID + hu];
            xw1[r] = Wxi[(size_t)idx[r] * HID + hu];
            xw2[r] = Wxf[(size_t)idx[r] * HID + hu];
            xw3[r] = Wxo[(size_t)idx[r] * HID + hu];
        }

        f32x4 acc[4][4];                    // [m-frag][gate]
#pragma unroll
        for (int m = 0; m < 4; ++m)
#pragma unroll
            for (int g = 0; g < 4; ++g) acc[m][g] = (f32x4){0.f, 0.f, 0.f, 0.f};

        // K-loop over my quarter: A from global (L2-shared), B from regs (kk<4) / LDS (kk>=4)
#pragma unroll
        for (int kk = 0; kk < 8; ++kk) {
            const int kel = (w << 8) + kk * 32 + (lHi << 3);
            bf16x8 a[4];
#pragma unroll
            for (int m = 0; m < 4; ++m)
                a[m] = *(const bf16x8*)(cur + (size_t)(r0 + m * 16 + lLo) * HID + kel);
            if (kk < 4) {
#pragma unroll
                for (int m = 0; m < 4; ++m)
#pragma unroll
                    for (int g = 0; g < 4; ++g)
                        acc[m][g] = __builtin_amdgcn_mfma_f32_16x16x32_bf16(a[m], B0[kk][g], acc[m][g], 0, 0, 0);
            } else {
                const int koff = (w << 8) + ((kk - 4) << 6) + (lHi << 4);   // 2*kl
#pragma unroll
                for (int g = 0; g < 4; ++g) {
                    bf16x8 bb = *(const bf16x8*)(lds + bbase[g] + (koff ^ bmask));
#pragma unroll
                    for (int m = 0; m < 4; ++m)
                        acc[m][g] = __builtin_amdgcn_mfma_f32_16x16x32_bf16(a[m], bb, acc[m][g], 0, 0, 0);
                }
            }
        }

        // ---- 2-phase cross-wave K-reduction (12KB buffer) + finalize
#pragma unroll
        for (int ph = 0; ph < 2; ++ph) {
            const int qa = ph * 2, qb = ph * 2 + 1;
#pragma unroll
            for (int q2 = 0; q2 < 2; ++q2) {
                const int q = (q2 == 0) ? qa : qb;
                if (q != w) {
                    const int src = (w < q) ? w : (w - 1);
                    const int slot = (q & 1) * 3 + src;
#pragma unroll
                    for (int g = 0; g < 4; ++g) {
                        union { unsigned short us[4]; unsigned long long v64; } pk;
#pragma unroll
                        for (int r = 0; r < 4; ++r) pk.us[r] = f2bf(acc[q][g][r]);
                        *(unsigned long long*)(pb + (slot * 4 + g) * 512 + l * 8) = pk.v64;
                    }
                }
            }
            __syncthreads();
            if (w == qa || w == qb) {
                float pre[4][4];
                const int sb = (w & 1) * 3;
#pragma unroll
                for (int g = 0; g < 4; ++g) {
#pragma unroll
                    for (int r = 0; r < 4; ++r) pre[g][r] = acc[w][g][r];
#pragma unroll
                    for (int s = 0; s < 3; ++s) {
                        union { unsigned short us[4]; unsigned long long v64; } pk;
                        pk.v64 = *(const unsigned long long*)(pb + ((sb + s) * 4 + g) * 512 + l * 8);
#pragma unroll
                        for (int r = 0; r < 4; ++r) pre[g][r] += bf2f(pk.us[r]);
                    }
                }
#pragma unroll
                for (int r = 0; r < 4; ++r) {
                    float gg = tanhf_(pre[0][r] + xw0[r] + vbg);
                    float ii = sigf  (pre[1][r] + xw1[r] + vbi);
                    float ff = sigf  (pre[2][r] + xw2[r] + vbf);
                    float oo = sigf  (pre[3][r] + xw3[r] + vbo);
                    cst[r] = gg * ii + cst[r] * ff;
                    float hv = tanhf_(cst[r]) * oo;
                    nxt[(size_t)(r0 + w * 16 + (lHi << 2) + r) * HID + hu] = f2bf(hv);
                }
            }
            __syncthreads();   // protect buffer reuse (phase B) / writes-before-barrier
        }

        // ---- device-wide barrier: distributed flags, agent scope, sticky guard
        __threadfence();
        __syncthreads();
        if (tid == 0)
            __hip_atomic_store(&flags[t * 256 + bid], 1u, __ATOMIC_RELEASE, __HIP_MEMORY_SCOPE_AGENT);
        if (!bailed) {
            unsigned guard = 0;
            while (__hip_atomic_load(&flags[t * 256 + tid], __ATOMIC_RELAXED, __HIP_MEMORY_SCOPE_AGENT) == 0u) {
                __builtin_amdgcn_s_sleep(2);
                if (++guard > (1u << 22)) { bailed = true; break; }
            }
        }
        if (bailed) {
            // sentinel: makes sync failure visible as absmax O(1), not a hang
#pragma unroll
            for (int r = 0; r < 4; ++r)
                nxt[(size_t)(r0 + w * 16 + (lHi << 2) + r) * HID + hu] = 0x42C8; // 100.0f
        }
        __syncthreads();
        __threadfence();                    // acquire: see other blocks' h stores
    }
}

// out[256][128] = h_512 @ W_hp + b_p  (h_512 lives in hbuf[0] since 512 is even)
__global__ void __launch_bounds__(256, 1) proj_kernel(
    const unsigned short* __restrict__ h, const float* __restrict__ Whp,
    const float* __restrict__ bp, float* __restrict__ out)
{
    __shared__ float red[4][256];
    const int tid  = threadIdx.x;
    const int n    = tid & 127;
    const int half = tid >> 7;
    const int b0   = blockIdx.x * 4;
    float s0 = 0.f, s1 = 0.f, s2 = 0.f, s3 = 0.f;
    for (int k = half * 512; k < half * 512 + 512; ++k) {
        float wv = Whp[(size_t)k * NCLS + n];
        s0 += bf2f(h[(size_t)(b0 + 0) * HID + k]) * wv;
        s1 += bf2f(h[(size_t)(b0 + 1) * HID + k]) * wv;
        s2 += bf2f(h[(size_t)(b0 + 2) * HID + k]) * wv;
        s3 += bf2f(h[(size_t)(b0 + 3) * HID + k]) * wv;
    }
    red[0][tid] = s0; red[1][tid] = s1; red[2][tid] = s2; red[3][tid] = s3;
    __syncthreads();
    if (tid < 128) {
#pragma unroll
        for (int j = 0; j < 4; ++j)
            out[(size_t)(b0 + j) * NCLS + tid] = red[j][tid] + red[j][tid + 128] + bp[tid];
    }
}

extern "C" void kernel_launch(void* const* d_in, const int* in_sizes, int n_in,
                              void* d_out, int out_size, void* d_ws, size_t ws_size,
                              hipStream_t stream) {
    const int*   x   = (const int*)  d_in[0];
    const float* Wxg = (const float*)d_in[1];
    const float* Whg = (const float*)d_in[2];
    const float* b_g = (const float*)d_in[3];
    const float* Wxi = (const float*)d_in[4];
    const float* Whi = (const float*)d_in[5];
    const float* b_i = (const float*)d_in[6];
    const float* Wxf = (const float*)d_in[7];
    const float* Whf = (const float*)d_in[8];
    const float* b_f = (const float*)d_in[9];
    const float* Wxo = (const float*)d_in[10];
    const float* Who = (const float*)d_in[11];
    const float* b_o = (const float*)d_in[12];
    const float* Whp = (const float*)d_in[13];
    const float* b_p = (const float*)d_in[14];
    float* out = (float*)d_out;

    char* ws = (char*)d_ws;
    unsigned short* hbuf  = (unsigned short*)ws;                          // 2*256*1024 bf16 = 1 MB
    int*            xT    = (int*)(ws + (1 << 20));                       // 512 KB
    unsigned int*   flags = (unsigned int*)(ws + (1 << 20) + (512*1024)); // 512*256*4 = 512 KB

    // re-zero per call: capture-safe, re-runs on every graph replay
    hipMemsetAsync(hbuf, 0, (size_t)BATCH * HID * sizeof(unsigned short), stream); // h_0 = 0
    hipMemsetAsync(flags, 0, (size_t)SEQT * 256 * sizeof(unsigned int), stream);

    xtrans_kernel<<<256, 256, 0, stream>>>(x, xT);

    const int ldsBytes = 65536 + 12288;     // B1-slice + exchange = 76 KB (<= 80 KB => 2 blocks/CU capacity)
    (void)hipFuncSetAttribute((const void*)lstm_pers,
                              hipFuncAttributeMaxDynamicSharedMemorySize, ldsBytes);
    lstm_pers<<<256, 256, ldsBytes, stream>>>(xT, Wxg, Whg, b_g, Wxi, Whi, b_i,
                                              Wxf, Whf, b_f, Wxo, Who, b_o, hbuf, flags);

    proj_kernel<<<64, 256, 0, stream>>>(hbuf, Whp, b_p, out);
}

// Round 5
// 11221.858 us; speedup vs baseline: 2.5308x; 2.5308x over previous
//
#include <hip/hip_runtime.h>
#include <stdint.h>

#define BATCH 256
#define SEQT  512
#define HID   1024
#define NCLS  128

using bf16x8 = __attribute__((ext_vector_type(8))) short;   // 8 bf16 (4 VGPRs)
using f32x4  = __attribute__((ext_vector_type(4))) float;
using i32x4  = __attribute__((ext_vector_type(4))) int;
using f32x4v = __attribute__((ext_vector_type(4))) float;

__device__ __forceinline__ unsigned short f2bf(float x) {
    unsigned u = __float_as_uint(x);
    u = u + 0x7FFFu + ((u >> 16) & 1u);          // round-to-nearest-even
    return (unsigned short)(u >> 16);
}
__device__ __forceinline__ float bf2f(unsigned short s) {
    return __uint_as_float(((unsigned)s) << 16);
}
__device__ __forceinline__ float sigf(float x) { return 1.f / (1.f + __expf(-x)); }
__device__ __forceinline__ float tanhf_(float x) {
    x = fminf(12.f, fmaxf(-12.f, x));
    float e = __expf(2.f * x);
    return (e - 1.f) / (e + 1.f);
}

// x[256][512] -> xT[512][256] so per-step index loads are contiguous int4
__global__ void xtrans_kernel(const int* __restrict__ x, int* __restrict__ xT) {
    int b = blockIdx.x;
    for (int t = threadIdx.x; t < SEQT; t += 256) xT[t * BATCH + b] = x[b * SEQT + t];
}

// Persistent LSTM. Grid = 256 x 256. Regular launch; co-residency by CAPACITY
// (LDS ~76KB, 120 VGPR => 2 blocks/CU capacity => non-residency impossible).
// Coherence protocol (NO wbl2 anywhere):
//   h-stores: packed 32-bit relaxed agent-scope stores (native dword write-through to MALL).
//   release : __syncthreads() (drains vmcnt in every wave) before tid0 counter add.
//   barrier : per-rg-panel counter (64 blocks), relaxed fetch_add + tid0 poll.
//   acquire : one agent acquire-fence per wave (buffer_inv only) before A-loads.
// Liveness: every wait is bounded; on timeout a block sets global abortf, goes
// permanently dead (keeps incrementing counters, writes 100.0 sentinels). All
// other blocks see abortf and die too => kernel ALWAYS terminates in bounded time.
__global__ void __launch_bounds__(256, 2) lstm_pers(
    const int* __restrict__ xT,
    const float* __restrict__ Wxg, const float* __restrict__ Whg, const float* __restrict__ b_g,
    const float* __restrict__ Wxi, const float* __restrict__ Whi, const float* __restrict__ b_i,
    const float* __restrict__ Wxf, const float* __restrict__ Whf, const float* __restrict__ b_f,
    const float* __restrict__ Wxo, const float* __restrict__ Who, const float* __restrict__ b_o,
    unsigned short* __restrict__ hbuf, unsigned int* __restrict__ cnt,
    unsigned int* __restrict__ abortf)
{
    extern __shared__ char lds[];
    const int tid = threadIdx.x;
    const int bid = blockIdx.x;
    const int w   = tid >> 6;       // wave 0..3: owns K-quarter w and output rows [16w,16w+16)
    const int l   = tid & 63;
    const int rg  = bid & 3;                                   // panel group: 64 blocks, XCD pair
    const int cg  = ((bid >> 3) << 1) | ((bid >> 2) & 1);      // hidden-unit group 0..63
    const int r0  = rg * 64;
    const int hu0 = cg * 16;
    const int lHi = l >> 4;         // 0..3
    const int lLo = l & 15;

    volatile int* bailp = (volatile int*)(lds + 77824);
    if (tid == 0) *bailp = 0;

    // ---- one-time B staging. pass p stages k with (k&255) in [128p,128p+128):
    //   kl in [0,512), k = (kl>>7)*256 + 128p + (kl&127)
    //   LDS byte = c*1024 + ((2*kl) ^ ((c&7)<<4))   (c = gate*16 + col)
    // p=0 -> bounced into B0 registers; p=1 -> persistent LDS (B1).
    bf16x8 B0[4][4];                // [kk][gate], kk = K-sub 0..3 of my quarter
    {
        const int j4 = (tid & 3) * 4;
        const int g  = (tid >> 2) & 3;
        const int kq = tid >> 4;                      // 0..15, 32 kl each
        const float* Wsrc = (g == 0) ? Whg : (g == 1) ? Whi : (g == 2) ? Whf : Who;
        for (int p = 0; p < 2; ++p) {
            for (int kl = kq * 32; kl < kq * 32 + 32; ++kl) {
                int k = ((kl >> 7) << 8) + (p << 7) + (kl & 127);
                f32x4v v = *(const f32x4v*)(Wsrc + (size_t)k * HID + hu0 + j4);
#pragma unroll
                for (int e = 0; e < 4; ++e) {
                    int c = g * 16 + j4 + e;
                    *(unsigned short*)(lds + c * 1024 + ((2 * kl) ^ ((c & 7) << 4))) = f2bf(v[e]);
                }
            }
            __syncthreads();
            if (p == 0) {
#pragma unroll
                for (int kk = 0; kk < 4; ++kk)
#pragma unroll
                    for (int g2 = 0; g2 < 4; ++g2) {
                        int c  = g2 * 16 + lLo;
                        int kl = w * 128 + kk * 32 + lHi * 8;
                        B0[kk][g2] = *(const bf16x8*)(lds + c * 1024 + ((2 * kl) ^ ((c & 7) << 4)));
                    }
                __syncthreads();   // before pass 1 overwrites the region
            }
        }
    }

    const int hu = hu0 + lLo;
    const float vbg = b_g[hu], vbi = b_i[hu], vbf = b_f[hu], vbo = b_o[hu];

    int bbase[4];
#pragma unroll
    for (int g = 0; g < 4; ++g) bbase[g] = (g * 16 + lLo) * 1024;
    const int bmask = (lLo & 7) << 4;

    char* pb = lds + 65536;                 // 12KB exchange buffer (2-phase)
    float cst[4] = {0.f, 0.f, 0.f, 0.f};    // c-state: 4 rows x 1 hu per lane
    bool mydead = false;                    // tid0's sticky death flag

    // xw prefetch state (computed for step t during step t-1's barrier window)
    float xw0[4], xw1[4], xw2[4], xw3[4];
    {
        i32x4 idx = *(const i32x4*)(xT + 0 * BATCH + r0 + w * 16 + (lHi << 2));
#pragma unroll
        for (int r = 0; r < 4; ++r) {
            xw0[r] = Wxg[(size_t)idx[r] * HID + hu];
            xw1[r] = Wxi[(size_t)idx[r] * HID + hu];
            xw2[r] = Wxf[(size_t)idx[r] * HID + hu];
            xw3[r] = Wxo[(size_t)idx[r] * HID + hu];
        }
    }
    __syncthreads();

    for (int t = 0; t < SEQT; ++t) {
        const unsigned short* cur = hbuf + (size_t)(t & 1) * BATCH * HID;
        unsigned short*       nxt = hbuf + (size_t)((t + 1) & 1) * BATCH * HID;

        f32x4 acc[4][4];                    // [m-frag][gate]
#pragma unroll
        for (int m = 0; m < 4; ++m)
#pragma unroll
            for (int g = 0; g < 4; ++g) acc[m][g] = (f32x4){0.f, 0.f, 0.f, 0.f};

        // K-loop over my quarter: A from global (L2-shared), B from regs (kk<4) / LDS (kk>=4)
#pragma unroll
        for (int kk = 0; kk < 8; ++kk) {
            const int kel = (w << 8) + kk * 32 + (lHi << 3);
            bf16x8 a[4];
#pragma unroll
            for (int m = 0; m < 4; ++m)
                a[m] = *(const bf16x8*)(cur + (size_t)(r0 + m * 16 + lLo) * HID + kel);
            if (kk < 4) {
#pragma unroll
                for (int m = 0; m < 4; ++m)
#pragma unroll
                    for (int g = 0; g < 4; ++g)
                        acc[m][g] = __builtin_amdgcn_mfma_f32_16x16x32_bf16(a[m], B0[kk][g], acc[m][g], 0, 0, 0);
            } else {
                const int koff = (w << 8) + ((kk - 4) << 6) + (lHi << 4);   // 2*kl
#pragma unroll
                for (int g = 0; g < 4; ++g) {
                    bf16x8 bb = *(const bf16x8*)(lds + bbase[g] + (koff ^ bmask));
#pragma unroll
                    for (int m = 0; m < 4; ++m)
                        acc[m][g] = __builtin_amdgcn_mfma_f32_16x16x32_bf16(a[m], bb, acc[m][g], 0, 0, 0);
                }
            }
        }

        // ---- 2-phase cross-wave K-reduction (12KB buffer) + finalize + packed h-store
        const int bailed = *bailp;
#pragma unroll
        for (int ph = 0; ph < 2; ++ph) {
            const int qa = ph * 2, qb = ph * 2 + 1;
#pragma unroll
            for (int q2 = 0; q2 < 2; ++q2) {
                const int q = (q2 == 0) ? qa : qb;
                if (q != w) {
                    const int src = (w < q) ? w : (w - 1);
                    const int slot = (q & 1) * 3 + src;
#pragma unroll
                    for (int g = 0; g < 4; ++g) {
                        union { unsigned short us[4]; unsigned long long v64; } pk;
#pragma unroll
                        for (int r = 0; r < 4; ++r) pk.us[r] = f2bf(acc[q][g][r]);
                        *(unsigned long long*)(pb + (slot * 4 + g) * 512 + l * 8) = pk.v64;
                    }
                }
            }
            __syncthreads();
            if (w == qa || w == qb) {
                float pre[4][4];
                const int sb = (w & 1) * 3;
#pragma unroll
                for (int g = 0; g < 4; ++g) {
#pragma unroll
                    for (int r = 0; r < 4; ++r) pre[g][r] = acc[w][g][r];
#pragma unroll
                    for (int s = 0; s < 3; ++s) {
                        union { unsigned short us[4]; unsigned long long v64; } pk;
                        pk.v64 = *(const unsigned long long*)(pb + ((sb + s) * 4 + g) * 512 + l * 8);
#pragma unroll
                        for (int r = 0; r < 4; ++r) pre[g][r] += bf2f(pk.us[r]);
                    }
                }
#pragma unroll
                for (int r = 0; r < 4; ++r) {
                    float gg = tanhf_(pre[0][r] + xw0[r] + vbg);
                    float ii = sigf  (pre[1][r] + xw1[r] + vbi);
                    float ff = sigf  (pre[2][r] + xw2[r] + vbf);
                    float oo = sigf  (pre[3][r] + xw3[r] + vbo);
                    cst[r] = gg * ii + cst[r] * ff;
                    float hv = tanhf_(cst[r]) * oo;
                    unsigned short hs = bailed ? (unsigned short)0x42C8 : f2bf(hv); // 100.0 sentinel
                    // pack lane-pair (adjacent hu) into one native dword store
                    unsigned pk32 = (unsigned)hs;
                    unsigned oth  = (unsigned)__shfl_xor((int)pk32, 1, 64) & 0xFFFFu;
                    if ((lLo & 1) == 0) {
                        unsigned v32 = pk32 | (oth << 16);
                        unsigned* p32 = (unsigned*)&nxt[(size_t)(r0 + w * 16 + (lHi << 2) + r) * HID + hu];
                        __hip_atomic_store(p32, v32, __ATOMIC_RELAXED, __HIP_MEMORY_SCOPE_AGENT);
                    }
                }
            }
            __syncthreads();   // protect exchange-buffer reuse
        }

        // ---- panel barrier (64 blocks sharing rg), no wbl2/no release fence:
        // syncthreads above already drained every wave's vmcnt => h visible at MALL.
        unsigned int* c = cnt + ((t * 4 + rg) << 4);   // 64B-padded counter
        if (tid == 0)
            __hip_atomic_fetch_add(c, 1u, __ATOMIC_RELAXED, __HIP_MEMORY_SCOPE_AGENT);

        // prefetch next step's one-hot projections during the wait (h-independent)
        {
            const int tn = (t + 1 < SEQT) ? t + 1 : t;
            i32x4 idx = *(const i32x4*)(xT + tn * BATCH + r0 + w * 16 + (lHi << 2));
#pragma unroll
            for (int r = 0; r < 4; ++r) {
                xw0[r] = Wxg[(size_t)idx[r] * HID + hu];
                xw1[r] = Wxi[(size_t)idx[r] * HID + hu];
                xw2[r] = Wxf[(size_t)idx[r] * HID + hu];
                xw3[r] = Wxo[(size_t)idx[r] * HID + hu];
            }
        }

        if (tid == 0 && !mydead) {
            unsigned guard = 0;
            for (;;) {
                if (__hip_atomic_load(c, __ATOMIC_RELAXED, __HIP_MEMORY_SCOPE_AGENT) >= 64u) break;
                if ((guard & 63u) == 0u &&
                    __hip_atomic_load(abortf, __ATOMIC_RELAXED, __HIP_MEMORY_SCOPE_AGENT) != 0u) {
                    mydead = true; *bailp = 1; break;          // someone else died: die too
                }
                __builtin_amdgcn_s_sleep(1);
                if (++guard > (1u << 17)) {                    // bounded window (~30ms)
                    __hip_atomic_store(abortf, 1u, __ATOMIC_RELAXED, __HIP_MEMORY_SCOPE_AGENT);
                    mydead = true; *bailp = 1; break;          // visible failure, no hang
                }
            }
        }
        __syncthreads();
        // acquire: invalidate stale L1/L2 copies (buffer_inv only — NO writeback)
        __builtin_amdgcn_fence(__ATOMIC_ACQUIRE, "agent");
    }
}

// out[256][128] = h_512 @ W_hp + b_p  (h_512 lives in hbuf[0] since 512 is even)
__global__ void __launch_bounds__(256, 1) proj_kernel(
    const unsigned short* __restrict__ h, const float* __restrict__ Whp,
    const float* __restrict__ bp, float* __restrict__ out)
{
    __shared__ float red[4][256];
    const int tid  = threadIdx.x;
    const int n    = tid & 127;
    const int half = tid >> 7;
    const int b0   = blockIdx.x * 4;
    float s0 = 0.f, s1 = 0.f, s2 = 0.f, s3 = 0.f;
    for (int k = half * 512; k < half * 512 + 512; ++k) {
        float wv = Whp[(size_t)k * NCLS + n];
        s0 += bf2f(h[(size_t)(b0 + 0) * HID + k]) * wv;
        s1 += bf2f(h[(size_t)(b0 + 1) * HID + k]) * wv;
        s2 += bf2f(h[(size_t)(b0 + 2) * HID + k]) * wv;
        s3 += bf2f(h[(size_t)(b0 + 3) * HID + k]) * wv;
    }
    red[0][tid] = s0; red[1][tid] = s1; red[2][tid] = s2; red[3][tid] = s3;
    __syncthreads();
    if (tid < 128) {
#pragma unroll
        for (int j = 0; j < 4; ++j)
            out[(size_t)(b0 + j) * NCLS + tid] = red[j][tid] + red[j][tid + 128] + bp[tid];
    }
}

extern "C" void kernel_launch(void* const* d_in, const int* in_sizes, int n_in,
                              void* d_out, int out_size, void* d_ws, size_t ws_size,
                              hipStream_t stream) {
    const int*   x   = (const int*)  d_in[0];
    const float* Wxg = (const float*)d_in[1];
    const float* Whg = (const float*)d_in[2];
    const float* b_g = (const float*)d_in[3];
    const float* Wxi = (const float*)d_in[4];
    const float* Whi = (const float*)d_in[5];
    const float* b_i = (const float*)d_in[6];
    const float* Wxf = (const float*)d_in[7];
    const float* Whf = (const float*)d_in[8];
    const float* b_f = (const float*)d_in[9];
    const float* Wxo = (const float*)d_in[10];
    const float* Who = (const float*)d_in[11];
    const float* b_o = (const float*)d_in[12];
    const float* Whp = (const float*)d_in[13];
    const float* b_p = (const float*)d_in[14];
    float* out = (float*)d_out;

    char* ws = (char*)d_ws;
    unsigned short* hbuf   = (unsigned short*)ws;                          // 2*256*1024 bf16 = 1 MB
    int*            xT     = (int*)(ws + (1 << 20));                       // 512 KB
    unsigned int*   cnt    = (unsigned int*)(ws + (1 << 20) + (512*1024)); // 512*4 counters, 64B-padded = 128 KB
    unsigned int*   abortf = (unsigned int*)(ws + (1 << 20) + (512*1024) + 131072); // 64 B

    // re-zero per call: capture-safe, re-runs on every graph replay
    hipMemsetAsync(hbuf, 0, (size_t)BATCH * HID * sizeof(unsigned short), stream); // h_0 = 0
    hipMemsetAsync(cnt, 0, (size_t)SEQT * 4 * 16 * sizeof(unsigned int) + 64, stream);

    xtrans_kernel<<<256, 256, 0, stream>>>(x, xT);

    const int ldsBytes = 65536 + 12288 + 64;   // B1 + exchange + bail flag (<=80KB => 2 blocks/CU)
    (void)hipFuncSetAttribute((const void*)lstm_pers,
                              hipFuncAttributeMaxDynamicSharedMemorySize, ldsBytes);
    lstm_pers<<<256, 256, ldsBytes, stream>>>(xT, Wxg, Whg, b_g, Wxi, Whi, b_i,
                                              Wxf, Whf, b_f, Wxo, Who, b_o, hbuf, cnt, abortf);

    proj_kernel<<<64, 256, 0, stream>>>(hbuf, Whp, b_p, out);
}

// Round 6
// 9598.531 us; speedup vs baseline: 2.9588x; 1.1691x over previous
//
#include <hip/hip_runtime.h>
#include <stdint.h>

#define BATCH 256
#define SEQT  512
#define HID   1024
#define NCLS  128

using bf16x8 = __attribute__((ext_vector_type(8))) short;   // 8 bf16 (4 VGPRs)
using f32x4  = __attribute__((ext_vector_type(4))) float;
using i32x4  = __attribute__((ext_vector_type(4))) int;
using f32x4v = __attribute__((ext_vector_type(4))) float;

__device__ __forceinline__ unsigned short f2bf(float x) {
    unsigned u = __float_as_uint(x);
    u = u + 0x7FFFu + ((u >> 16) & 1u);          // round-to-nearest-even
    return (unsigned short)(u >> 16);
}
__device__ __forceinline__ float bf2f(unsigned short s) {
    return __uint_as_float(((unsigned)s) << 16);
}
__device__ __forceinline__ float sigf(float x) { return 1.f / (1.f + __expf(-x)); }
__device__ __forceinline__ float tanhf_(float x) {
    x = fminf(12.f, fmaxf(-12.f, x));
    float e = __expf(2.f * x);
    return (e - 1.f) / (e + 1.f);
}

// agent-coherent 16B load: bypasses L1/L2 (sc1), reads the MALL coherence point.
// No waitcnt inside — caller manages counted vmcnt (m218 pattern).
__device__ __forceinline__ void ld_a_sc1(bf16x8& d, const unsigned short* p) {
    asm volatile("global_load_dwordx4 %0, %1, off sc1" : "=v"(d) : "v"(p));
}

// x[256][512] -> xT[512][256] so per-step index loads are contiguous int4
__global__ void xtrans_kernel(const int* __restrict__ x, int* __restrict__ xT) {
    int b = blockIdx.x;
    for (int t = threadIdx.x; t < SEQT; t += 256) xT[t * BATCH + b] = x[b * SEQT + t];
}

// Persistent LSTM. Grid = 256 x 256. Regular launch; co-residency by CAPACITY
// (LDS ~76KB, ~<=200 VGPR => 2 blocks/CU capacity => non-residency impossible).
// Coherence protocol — NO fences, NO invalidates, NO L2 churn:
//   h-stores: packed 32-bit relaxed agent-scope (sc1) stores -> MALL.
//   release : __syncthreads() drains vmcnt in every wave before tid0 counter add.
//   barrier : per-rg-panel counter (64 blocks), relaxed fetch_add + tid0 poll.
//   acquire : A-loads are sc1 (bypass) loads -> always MALL-fresh; weights/xT
//             stay ordinarily cached (read-only, never invalidated).
// Liveness: every wait bounded; on timeout set global abortf, go permanently
// dead (keep counting, write 100.0 sentinels) => always terminates.
__global__ void __launch_bounds__(256, 2) lstm_pers(
    const int* __restrict__ xT,
    const float* __restrict__ Wxg, const float* __restrict__ Whg, const float* __restrict__ b_g,
    const float* __restrict__ Wxi, const float* __restrict__ Whi, const float* __restrict__ b_i,
    const float* __restrict__ Wxf, const float* __restrict__ Whf, const float* __restrict__ b_f,
    const float* __restrict__ Wxo, const float* __restrict__ Who, const float* __restrict__ b_o,
    unsigned short* __restrict__ hbuf, unsigned int* __restrict__ cnt,
    unsigned int* __restrict__ abortf)
{
    extern __shared__ char lds[];
    const int tid = threadIdx.x;
    const int bid = blockIdx.x;
    const int w   = tid >> 6;       // wave 0..3: owns K-quarter w and output rows [16w,16w+16)
    const int l   = tid & 63;
    const int rg  = bid & 3;                                   // panel group: 64 blocks, XCD pair
    const int cg  = ((bid >> 3) << 1) | ((bid >> 2) & 1);      // hidden-unit group 0..63
    const int r0  = rg * 64;
    const int hu0 = cg * 16;
    const int lHi = l >> 4;         // 0..3
    const int lLo = l & 15;

    volatile int* bailp = (volatile int*)(lds + 77824);
    if (tid == 0) *bailp = 0;

    // ---- one-time B staging. pass p stages k with (k&255) in [128p,128p+128):
    //   kl in [0,512), k = (kl>>7)*256 + 128p + (kl&127)
    //   LDS byte = c*1024 + ((2*kl) ^ ((c&7)<<4))   (c = gate*16 + col)
    // p=0 -> bounced into B0 registers; p=1 -> persistent LDS (B1).
    bf16x8 B0[4][4];                // [kk][gate], kk = K-sub 0..3 of my quarter
    {
        const int j4 = (tid & 3) * 4;
        const int g  = (tid >> 2) & 3;
        const int kq = tid >> 4;                      // 0..15, 32 kl each
        const float* Wsrc = (g == 0) ? Whg : (g == 1) ? Whi : (g == 2) ? Whf : Who;
        for (int p = 0; p < 2; ++p) {
            for (int kl = kq * 32; kl < kq * 32 + 32; ++kl) {
                int k = ((kl >> 7) << 8) + (p << 7) + (kl & 127);
                f32x4v v = *(const f32x4v*)(Wsrc + (size_t)k * HID + hu0 + j4);
#pragma unroll
                for (int e = 0; e < 4; ++e) {
                    int c = g * 16 + j4 + e;
                    *(unsigned short*)(lds + c * 1024 + ((2 * kl) ^ ((c & 7) << 4))) = f2bf(v[e]);
                }
            }
            __syncthreads();
            if (p == 0) {
#pragma unroll
                for (int kk = 0; kk < 4; ++kk)
#pragma unroll
                    for (int g2 = 0; g2 < 4; ++g2) {
                        int c  = g2 * 16 + lLo;
                        int kl = w * 128 + kk * 32 + lHi * 8;
                        B0[kk][g2] = *(const bf16x8*)(lds + c * 1024 + ((2 * kl) ^ ((c & 7) << 4)));
                    }
                __syncthreads();   // before pass 1 overwrites the region
            }
        }
    }

    const int hu = hu0 + lLo;
    const float vbg = b_g[hu], vbi = b_i[hu], vbf = b_f[hu], vbo = b_o[hu];

    int bbase[4];
#pragma unroll
    for (int g = 0; g < 4; ++g) bbase[g] = (g * 16 + lLo) * 1024;
    const int bmask = (lLo & 7) << 4;

    char* pb = lds + 65536;                 // 12KB exchange buffer (2-phase)
    float cst[4] = {0.f, 0.f, 0.f, 0.f};    // c-state: 4 rows x 1 hu per lane
    bool mydead = false;                    // tid0's sticky death flag

    // per-lane A row bases (row = r0 + m*16 + lLo), K-quarter origin w*256 + lHi*8
    const unsigned short* arow[4];
    // filled per step from cur

    // xw prefetch state (computed for step t during step t-1's barrier window)
    float xw0[4], xw1[4], xw2[4], xw3[4];
    {
        i32x4 idx = *(const i32x4*)(xT + 0 * BATCH + r0 + w * 16 + (lHi << 2));
#pragma unroll
        for (int r = 0; r < 4; ++r) {
            xw0[r] = Wxg[(size_t)idx[r] * HID + hu];
            xw1[r] = Wxi[(size_t)idx[r] * HID + hu];
            xw2[r] = Wxf[(size_t)idx[r] * HID + hu];
            xw3[r] = Wxo[(size_t)idx[r] * HID + hu];
        }
    }
    __syncthreads();

    for (int t = 0; t < SEQT; ++t) {
        const unsigned short* cur = hbuf + (size_t)(t & 1) * BATCH * HID;
        unsigned short*       nxt = hbuf + (size_t)((t + 1) & 1) * BATCH * HID;

#pragma unroll
        for (int m = 0; m < 4; ++m)
            arow[m] = cur + (size_t)(r0 + m * 16 + lLo) * HID + ((w << 8) + (lHi << 3));

        f32x4 acc[4][4];                    // [m-frag][gate]
#pragma unroll
        for (int m = 0; m < 4; ++m)
#pragma unroll
            for (int g = 0; g < 4; ++g) acc[m][g] = (f32x4){0.f, 0.f, 0.f, 0.f};

        // ---- K-loop, 2-deep pipelined sc1 A-loads with counted vmcnt.
        bf16x8 aA[4], aB[4];
#pragma unroll
        for (int m = 0; m < 4; ++m) ld_a_sc1(aA[m], arow[m] + 0 * 32);
#pragma unroll
        for (int kk = 0; kk < 8; ++kk) {
            bf16x8* curA = (kk & 1) ? aB : aA;
            bf16x8* nxtA = (kk & 1) ? aA : aB;
            if (kk < 7) {
#pragma unroll
                for (int m = 0; m < 4; ++m) ld_a_sc1(nxtA[m], arow[m] + (kk + 1) * 32);
                asm volatile("s_waitcnt vmcnt(4)" ::: "memory");   // group kk complete
            } else {
                asm volatile("s_waitcnt vmcnt(0)" ::: "memory");
            }
            __builtin_amdgcn_sched_barrier(0);
            if (kk < 4) {
#pragma unroll
                for (int m = 0; m < 4; ++m)
#pragma unroll
                    for (int g = 0; g < 4; ++g)
                        acc[m][g] = __builtin_amdgcn_mfma_f32_16x16x32_bf16(curA[m], B0[kk][g], acc[m][g], 0, 0, 0);
            } else {
                const int koff = (w << 8) + ((kk - 4) << 6) + (lHi << 4);   // 2*kl
#pragma unroll
                for (int g = 0; g < 4; ++g) {
                    bf16x8 bb = *(const bf16x8*)(lds + bbase[g] + (koff ^ bmask));
#pragma unroll
                    for (int m = 0; m < 4; ++m)
                        acc[m][g] = __builtin_amdgcn_mfma_f32_16x16x32_bf16(curA[m], bb, acc[m][g], 0, 0, 0);
                }
            }
        }

        // ---- 2-phase cross-wave K-reduction (12KB buffer) + finalize + packed h-store
        const int bailed = *bailp;
#pragma unroll
        for (int ph = 0; ph < 2; ++ph) {
            const int qa = ph * 2, qb = ph * 2 + 1;
#pragma unroll
            for (int q2 = 0; q2 < 2; ++q2) {
                const int q = (q2 == 0) ? qa : qb;
                if (q != w) {
                    const int src = (w < q) ? w : (w - 1);
                    const int slot = (q & 1) * 3 + src;
#pragma unroll
                    for (int g = 0; g < 4; ++g) {
                        union { unsigned short us[4]; unsigned long long v64; } pk;
#pragma unroll
                        for (int r = 0; r < 4; ++r) pk.us[r] = f2bf(acc[q][g][r]);
                        *(unsigned long long*)(pb + (slot * 4 + g) * 512 + l * 8) = pk.v64;
                    }
                }
            }
            __syncthreads();
            if (w == qa || w == qb) {
                float pre[4][4];
                const int sb = (w & 1) * 3;
#pragma unroll
                for (int g = 0; g < 4; ++g) {
#pragma unroll
                    for (int r = 0; r < 4; ++r) pre[g][r] = acc[w][g][r];
#pragma unroll
                    for (int s = 0; s < 3; ++s) {
                        union { unsigned short us[4]; unsigned long long v64; } pk;
                        pk.v64 = *(const unsigned long long*)(pb + ((sb + s) * 4 + g) * 512 + l * 8);
#pragma unroll
                        for (int r = 0; r < 4; ++r) pre[g][r] += bf2f(pk.us[r]);
                    }
                }
#pragma unroll
                for (int r = 0; r < 4; ++r) {
                    float gg = tanhf_(pre[0][r] + xw0[r] + vbg);
                    float ii = sigf  (pre[1][r] + xw1[r] + vbi);
                    float ff = sigf  (pre[2][r] + xw2[r] + vbf);
                    float oo = sigf  (pre[3][r] + xw3[r] + vbo);
                    cst[r] = gg * ii + cst[r] * ff;
                    float hv = tanhf_(cst[r]) * oo;
                    unsigned short hs = bailed ? (unsigned short)0x42C8 : f2bf(hv); // 100.0 sentinel
                    // pack lane-pair (adjacent hu) into one native dword agent store
                    unsigned pk32 = (unsigned)hs;
                    unsigned oth  = (unsigned)__shfl_xor((int)pk32, 1, 64) & 0xFFFFu;
                    if ((lLo & 1) == 0) {
                        unsigned v32 = pk32 | (oth << 16);
                        unsigned* p32 = (unsigned*)&nxt[(size_t)(r0 + w * 16 + (lHi << 2) + r) * HID + hu];
                        __hip_atomic_store(p32, v32, __ATOMIC_RELAXED, __HIP_MEMORY_SCOPE_AGENT);
                    }
                }
            }
            __syncthreads();   // protect exchange-buffer reuse
        }

        // ---- panel barrier (64 blocks sharing rg):
        // syncthreads above drained every wave's vmcnt => h (sc1) visible at MALL.
        unsigned int* c = cnt + ((t * 4 + rg) << 4);   // 64B-padded counter
        if (tid == 0)
            __hip_atomic_fetch_add(c, 1u, __ATOMIC_RELAXED, __HIP_MEMORY_SCOPE_AGENT);

        // prefetch next step's one-hot projections during the wait (h-independent)
        {
            const int tn = (t + 1 < SEQT) ? t + 1 : t;
            i32x4 idx = *(const i32x4*)(xT + tn * BATCH + r0 + w * 16 + (lHi << 2));
#pragma unroll
            for (int r = 0; r < 4; ++r) {
                xw0[r] = Wxg[(size_t)idx[r] * HID + hu];
                xw1[r] = Wxi[(size_t)idx[r] * HID + hu];
                xw2[r] = Wxf[(size_t)idx[r] * HID + hu];
                xw3[r] = Wxo[(size_t)idx[r] * HID + hu];
            }
        }

        if (tid == 0 && !mydead) {
            unsigned guard = 0;
            for (;;) {
                if (__hip_atomic_load(c, __ATOMIC_RELAXED, __HIP_MEMORY_SCOPE_AGENT) >= 64u) break;
                if ((guard & 63u) == 0u &&
                    __hip_atomic_load(abortf, __ATOMIC_RELAXED, __HIP_MEMORY_SCOPE_AGENT) != 0u) {
                    mydead = true; *bailp = 1; break;          // someone else died: die too
                }
                __builtin_amdgcn_s_sleep(1);
                if (++guard > (1u << 17)) {                    // bounded window (~30ms)
                    __hip_atomic_store(abortf, 1u, __ATOMIC_RELAXED, __HIP_MEMORY_SCOPE_AGENT);
                    mydead = true; *bailp = 1; break;          // visible failure, no hang
                }
            }
        }
        __syncthreads();
        // NO fence: sc1 A-loads next iteration read the coherence point directly.
    }
}

// out[256][128] = h_512 @ W_hp + b_p  (h_512 lives in hbuf[0] since 512 is even)
__global__ void __launch_bounds__(256, 1) proj_kernel(
    const unsigned short* __restrict__ h, const float* __restrict__ Whp,
    const float* __restrict__ bp, float* __restrict__ out)
{
    __shared__ float red[4][256];
    const int tid  = threadIdx.x;
    const int n    = tid & 127;
    const int half = tid >> 7;
    const int b0   = blockIdx.x * 4;
    float s0 = 0.f, s1 = 0.f, s2 = 0.f, s3 = 0.f;
    for (int k = half * 512; k < half * 512 + 512; ++k) {
        float wv = Whp[(size_t)k * NCLS + n];
        s0 += bf2f(h[(size_t)(b0 + 0) * HID + k]) * wv;
        s1 += bf2f(h[(size_t)(b0 + 1) * HID + k]) * wv;
        s2 += bf2f(h[(size_t)(b0 + 2) * HID + k]) * wv;
        s3 += bf2f(h[(size_t)(b0 + 3) * HID + k]) * wv;
    }
    red[0][tid] = s0; red[1][tid] = s1; red[2][tid] = s2; red[3][tid] = s3;
    __syncthreads();
    if (tid < 128) {
#pragma unroll
        for (int j = 0; j < 4; ++j)
            out[(size_t)(b0 + j) * NCLS + tid] = red[j][tid] + red[j][tid + 128] + bp[tid];
    }
}

extern "C" void kernel_launch(void* const* d_in, const int* in_sizes, int n_in,
                              void* d_out, int out_size, void* d_ws, size_t ws_size,
                              hipStream_t stream) {
    const int*   x   = (const int*)  d_in[0];
    const float* Wxg = (const float*)d_in[1];
    const float* Whg = (const float*)d_in[2];
    const float* b_g = (const float*)d_in[3];
    const float* Wxi = (const float*)d_in[4];
    const float* Whi = (const float*)d_in[5];
    const float* b_i = (const float*)d_in[6];
    const float* Wxf = (const float*)d_in[7];
    const float* Whf = (const float*)d_in[8];
    const float* b_f = (const float*)d_in[9];
    const float* Wxo = (const float*)d_in[10];
    const float* Who = (const float*)d_in[11];
    const float* b_o = (const float*)d_in[12];
    const float* Whp = (const float*)d_in[13];
    const float* b_p = (const float*)d_in[14];
    float* out = (float*)d_out;

    char* ws = (char*)d_ws;
    unsigned short* hbuf   = (unsigned short*)ws;                          // 2*256*1024 bf16 = 1 MB
    int*            xT     = (int*)(ws + (1 << 20));                       // 512 KB
    unsigned int*   cnt    = (unsigned int*)(ws + (1 << 20) + (512*1024)); // 512*4 counters, 64B-padded = 128 KB
    unsigned int*   abortf = (unsigned int*)(ws + (1 << 20) + (512*1024) + 131072); // 64 B

    // re-zero per call: capture-safe, re-runs on every graph replay
    hipMemsetAsync(hbuf, 0, (size_t)BATCH * HID * sizeof(unsigned short), stream); // h_0 = 0
    hipMemsetAsync(cnt, 0, (size_t)SEQT * 4 * 16 * sizeof(unsigned int) + 64, stream);

    xtrans_kernel<<<256, 256, 0, stream>>>(x, xT);

    const int ldsBytes = 65536 + 12288 + 64;   // B1 + exchange + bail flag (<=80KB => 2 blocks/CU)
    (void)hipFuncSetAttribute((const void*)lstm_pers,
                              hipFuncAttributeMaxDynamicSharedMemorySize, ldsBytes);
    lstm_pers<<<256, 256, ldsBytes, stream>>>(xT, Wxg, Whg, b_g, Wxi, Whi, b_i,
                                              Wxf, Whf, b_f, Wxo, Who, b_o, hbuf, cnt, abortf);

    proj_kernel<<<64, 256, 0, stream>>>(hbuf, Whp, b_p, out);
}

// Round 7
// 6742.898 us; speedup vs baseline: 4.2119x; 1.4235x over previous
//
#include <hip/hip_runtime.h>
#include <stdint.h>

#define BATCH 256
#define SEQT  512
#define HID   1024
#define NCLS  128

using bf16x8 = __attribute__((ext_vector_type(8))) short;   // 8 bf16 (4 VGPRs)
using f32x4  = __attribute__((ext_vector_type(4))) float;
using i32x4  = __attribute__((ext_vector_type(4))) int;
using f32x4v = __attribute__((ext_vector_type(4))) float;

__device__ __forceinline__ unsigned short f2bf(float x) {
    unsigned u = __float_as_uint(x);
    u = u + 0x7FFFu + ((u >> 16) & 1u);          // round-to-nearest-even
    return (unsigned short)(u >> 16);
}
__device__ __forceinline__ float bf2f(unsigned short s) {
    return __uint_as_float(((unsigned)s) << 16);
}
__device__ __forceinline__ float sigf(float x) { return 1.f / (1.f + __expf(-x)); }
__device__ __forceinline__ float tanhf_(float x) {
    x = fminf(12.f, fmaxf(-12.f, x));
    float e = __expf(2.f * x);
    return (e - 1.f) / (e + 1.f);
}

// L1-bypassing 16B load (sc0): reads the XCD's shared L2 (the intra-XCD
// coherence point). No waitcnt inside — caller manages counted vmcnt.
__device__ __forceinline__ void ld_a_sc0(bf16x8& d, const unsigned short* p) {
    asm volatile("global_load_dwordx4 %0, %1, off sc0" : "=v"(d) : "v"(p));
}

__device__ __forceinline__ unsigned ag_load(unsigned* p) {
    return __hip_atomic_load(p, __ATOMIC_RELAXED, __HIP_MEMORY_SCOPE_AGENT);
}
__device__ __forceinline__ void ag_store(unsigned* p, unsigned v) {
    __hip_atomic_store(p, v, __ATOMIC_RELAXED, __HIP_MEMORY_SCOPE_AGENT);
}
__device__ __forceinline__ unsigned ag_add(unsigned* p) {
    return __hip_atomic_fetch_add(p, 1u, __ATOMIC_RELAXED, __HIP_MEMORY_SCOPE_AGENT);
}

// bounded wait until *p >= target (agent/MALL). false => aborted/timeout.
__device__ __forceinline__ bool wait_ge(unsigned* p, unsigned target,
                                        unsigned* abortf, unsigned limit) {
    unsigned guard = 0;
    for (;;) {
        if (ag_load(p) >= target) return true;
        if ((guard & 63u) == 0u && ag_load(abortf) != 0u) return false;
        __builtin_amdgcn_s_sleep(1);
        if (++guard > limit) { ag_store(abortf, 1u); return false; }
    }
}

// x[256][512] -> xT[512][256] so per-step index loads are contiguous int4
__global__ void xtrans_kernel(const int* __restrict__ x, int* __restrict__ xT) {
    int b = blockIdx.x;
    for (int t = threadIdx.x; t < SEQT; t += 256) xT[t * BATCH + b] = x[b * SEQT + t];
}

// Persistent LSTM, batch-partitioned by XCD. Grid = 512 x 256 (2 blocks/CU by
// capacity: ~76KB LDS, <=256 VGPR). Domain d = XCD d (runtime-discovered via
// s_getreg XCC_ID) owns batch rows [32d,32d+32); its 64 blocks cover all 4096
// cols (cgrp via per-XCD ticket). h panel stays in the XCD's L2:
//   h-stores: workgroup-scope dword stores (write-through L1 -> L2).
//   A-loads : sc0 (bypass L1, hit shared L2).  NO fences, NO MALL data traffic.
//   barrier : per-(t,domain) counter at MALL (agent atomics), 64 participants.
// Liveness: all waits bounded; timeout/anomaly -> abortf + 100.0 sentinels
// (visible failure), never a hang.
__global__ void __launch_bounds__(256, 2) lstm_pers(
    const int* __restrict__ xT,
    const float* __restrict__ Wxg, const float* __restrict__ Whg, const float* __restrict__ b_g,
    const float* __restrict__ Wxi, const float* __restrict__ Whi, const float* __restrict__ b_i,
    const float* __restrict__ Wxf, const float* __restrict__ Whf, const float* __restrict__ b_f,
    const float* __restrict__ Wxo, const float* __restrict__ Who, const float* __restrict__ b_o,
    unsigned short* __restrict__ hbuf, unsigned int* __restrict__ cnt,
    unsigned int* __restrict__ misc)
{
    extern __shared__ char lds[];
    const int tid = threadIdx.x;
    const int w   = tid >> 6;       // wave 0..3: K-quarter w; waves 0,1 finalize frag 0,1
    const int l   = tid & 63;
    const int lHi = l >> 4;         // 0..3
    const int lLo = l & 15;

    volatile int* bailp  = (volatile int*)(lds + 77824);
    volatile int* bcast  = (volatile int*)(lds + 77828);   // [0]=slot, [1]=xcc
    unsigned* ticket = misc;          // [0..7]
    unsigned* rz1    = misc + 8;
    unsigned* rz2    = misc + 9;
    unsigned* abortf = misc + 10;

    if (tid == 0) {
        *bailp = 0;
        unsigned xcc;
        asm volatile("s_getreg_b32 %0, hwreg(20, 0, 32)" : "=s"(xcc));  // HW_REG_XCC_ID
        xcc &= 7u;
        unsigned slot = ag_add(&ticket[xcc]);
        bcast[0] = (int)slot;
        bcast[1] = (int)xcc;
    }
    __syncthreads();
    const int slot   = bcast[0];
    const int domain = bcast[1];

    if (slot >= 64) {               // uneven placement: abort visibly, exit
        if (tid == 0) ag_store(abortf, 1u);
        return;
    }
    const int r0  = domain * 32;    // my domain's batch rows
    const int hu0 = slot * 16;      // my 16 hidden units (cols g|i|f|o x 16)

    // ---- one-time B staging (R6 layout). pass p stages k with (k&255) in
    // [128p,128p+128): kl in [0,512), k=(kl>>7)*256+128p+(kl&127);
    // LDS byte = c*1024 + ((2*kl) ^ ((c&7)<<4)), c = gate*16 + col.
    // p=0 -> bounced into B0 registers; p=1 -> persistent LDS (B1).
    bf16x8 B0[4][4];                // [kk][gate], kk = K-sub 0..3 of my quarter
    {
        const int j4 = (tid & 3) * 4;
        const int g  = (tid >> 2) & 3;
        const int kq = tid >> 4;                      // 0..15, 32 kl each
        const float* Wsrc = (g == 0) ? Whg : (g == 1) ? Whi : (g == 2) ? Whf : Who;
        for (int p = 0; p < 2; ++p) {
            for (int kl = kq * 32; kl < kq * 32 + 32; ++kl) {
                int k = ((kl >> 7) << 8) + (p << 7) + (kl & 127);
                f32x4v v = *(const f32x4v*)(Wsrc + (size_t)k * HID + hu0 + j4);
#pragma unroll
                for (int e = 0; e < 4; ++e) {
                    int c = g * 16 + j4 + e;
                    *(unsigned short*)(lds + c * 1024 + ((2 * kl) ^ ((c & 7) << 4))) = f2bf(v[e]);
                }
            }
            __syncthreads();
            if (p == 0) {
#pragma unroll
                for (int kk = 0; kk < 4; ++kk)
#pragma unroll
                    for (int g2 = 0; g2 < 4; ++g2) {
                        int c  = g2 * 16 + lLo;
                        int kl = w * 128 + kk * 32 + lHi * 8;
                        B0[kk][g2] = *(const bf16x8*)(lds + c * 1024 + ((2 * kl) ^ ((c & 7) << 4)));
                    }
                __syncthreads();   // before pass 1 overwrites the region
            }
        }
    }

    // ---- rendezvous 1: all 512 blocks scheduled & ticketed
    bool dead = false;
    if (tid == 0) {
        ag_add(rz1);
        if (!wait_ge(rz1, 512u, abortf, (1u << 18))) { dead = true; *bailp = 1; }
    }
    __syncthreads();

    // ---- self-zero my h_0 slice (32 rows x 16 hu = 1KB) via L2 path
    {
        unsigned* hz = (unsigned*)(hbuf) + (size_t)(r0 + (tid >> 3)) * (HID / 2) + slot * 8 + (tid & 7);
        __hip_atomic_store(hz, 0u, __ATOMIC_RELAXED, __HIP_MEMORY_SCOPE_WORKGROUP);
    }
    __syncthreads();

    // ---- rendezvous 2: zeros visible domain-wide before t=0
    if (tid == 0 && !dead) {
        ag_add(rz2);
        if (!wait_ge(rz2, 512u, abortf, (1u << 18))) { dead = true; *bailp = 1; }
    }
    __syncthreads();

    const int hu = hu0 + lLo;
    const float vbg = b_g[hu], vbi = b_i[hu], vbf = b_f[hu], vbo = b_o[hu];

    int bbase[4];
#pragma unroll
    for (int g = 0; g < 4; ++g) bbase[g] = (g * 16 + lLo) * 1024;
    const int bmask = (lLo & 7) << 4;

    char* pb = lds + 65536;                 // 12KB exchange buffer
    float cst[4] = {0.f, 0.f, 0.f, 0.f};    // c-state (waves 0,1): 4 rows x 1 hu

    // xw prefetch (waves 0,1 = finalizers of frag w)
    float xw0[4], xw1[4], xw2[4], xw3[4];
    if (w < 2) {
        i32x4 idx = *(const i32x4*)(xT + 0 * BATCH + r0 + w * 16 + (lHi << 2));
#pragma unroll
        for (int r = 0; r < 4; ++r) {
            xw0[r] = Wxg[(size_t)idx[r] * HID + hu];
            xw1[r] = Wxi[(size_t)idx[r] * HID + hu];
            xw2[r] = Wxf[(size_t)idx[r] * HID + hu];
            xw3[r] = Wxo[(size_t)idx[r] * HID + hu];
        }
    }

    for (int t = 0; t < SEQT; ++t) {
        const unsigned short* cur = hbuf + (size_t)(t & 1) * BATCH * HID;
        unsigned short*       nxt = hbuf + (size_t)((t + 1) & 1) * BATCH * HID;

        const unsigned short* arow0 = cur + (size_t)(r0 + lLo) * HID + ((w << 8) + (lHi << 3));
        const unsigned short* arow1 = arow0 + 16 * HID;

        f32x4 acc[2][4];                    // [m-frag][gate]
#pragma unroll
        for (int m = 0; m < 2; ++m)
#pragma unroll
            for (int g = 0; g < 4; ++g) acc[m][g] = (f32x4){0.f, 0.f, 0.f, 0.f};

        // ---- K-loop over my quarter: A sc0 (L2), B from regs (kk<4) / LDS
        bf16x8 aA[2], aB[2];
        ld_a_sc0(aA[0], arow0);
        ld_a_sc0(aA[1], arow1);
#pragma unroll
        for (int kk = 0; kk < 8; ++kk) {
            bf16x8* curA = (kk & 1) ? aB : aA;
            bf16x8* nxtA = (kk & 1) ? aA : aB;
            if (kk < 7) {
                ld_a_sc0(nxtA[0], arow0 + (kk + 1) * 32);
                ld_a_sc0(nxtA[1], arow1 + (kk + 1) * 32);
                asm volatile("s_waitcnt vmcnt(2)" ::: "memory");
            } else {
                asm volatile("s_waitcnt vmcnt(0)" ::: "memory");
            }
            __builtin_amdgcn_sched_barrier(0);
            if (kk < 4) {
#pragma unroll
                for (int m = 0; m < 2; ++m)
#pragma unroll
                    for (int g = 0; g < 4; ++g)
                        acc[m][g] = __builtin_amdgcn_mfma_f32_16x16x32_bf16(curA[m], B0[kk][g], acc[m][g], 0, 0, 0);
            } else {
                const int koff = (w << 8) + ((kk - 4) << 6) + (lHi << 4);
#pragma unroll
                for (int g = 0; g < 4; ++g) {
                    bf16x8 bb = *(const bf16x8*)(lds + bbase[g] + (koff ^ bmask));
#pragma unroll
                    for (int m = 0; m < 2; ++m)
                        acc[m][g] = __builtin_amdgcn_mfma_f32_16x16x32_bf16(curA[m], bb, acc[m][g], 0, 0, 0);
                }
            }
        }

        // ---- cross-wave K-reduction: frag m's partials go to finalizer wave m
#pragma unroll
        for (int m = 0; m < 2; ++m) {
            if (w != m) {
                const int src = (w < m) ? w : (w - 1);   // 0..2 among non-owners
#pragma unroll
                for (int g = 0; g < 4; ++g) {
                    union { unsigned short us[4]; unsigned long long v64; } pk;
#pragma unroll
                    for (int r = 0; r < 4; ++r) pk.us[r] = f2bf(acc[m][g][r]);
                    *(unsigned long long*)(pb + ((m * 3 + src) * 4 + g) * 512 + l * 8) = pk.v64;
                }
            }
        }
        __syncthreads();

        const int bailed = *bailp;
        if (w < 2) {
            const int m = w;
            float pre[4][4];
#pragma unroll
            for (int g = 0; g < 4; ++g) {
#pragma unroll
                for (int r = 0; r < 4; ++r) pre[g][r] = acc[m][g][r];
#pragma unroll
                for (int s = 0; s < 3; ++s) {
                    union { unsigned short us[4]; unsigned long long v64; } pk;
                    pk.v64 = *(const unsigned long long*)(pb + ((m * 3 + s) * 4 + g) * 512 + l * 8);
#pragma unroll
                    for (int r = 0; r < 4; ++r) pre[g][r] += bf2f(pk.us[r]);
                }
            }
#pragma unroll
            for (int r = 0; r < 4; ++r) {
                float gg = tanhf_(pre[0][r] + xw0[r] + vbg);
                float ii = sigf  (pre[1][r] + xw1[r] + vbi);
                float ff = sigf  (pre[2][r] + xw2[r] + vbf);
                float oo = sigf  (pre[3][r] + xw3[r] + vbo);
                cst[r] = gg * ii + cst[r] * ff;
                float hv = tanhf_(cst[r]) * oo;
                unsigned short hs = bailed ? (unsigned short)0x42C8 : f2bf(hv); // 100.0 sentinel
                // pack lane-pair (adjacent hu) into one dword store (L1 write-through -> L2)
                unsigned pk32 = (unsigned)hs;
                unsigned oth  = (unsigned)__shfl_xor((int)pk32, 1, 64) & 0xFFFFu;
                if ((lLo & 1) == 0) {
                    unsigned v32 = pk32 | (oth << 16);
                    unsigned* p32 = (unsigned*)&nxt[(size_t)(r0 + m * 16 + (lHi << 2) + r) * HID + hu];
                    __hip_atomic_store(p32, v32, __ATOMIC_RELAXED, __HIP_MEMORY_SCOPE_WORKGROUP);
                }
            }
        }
        __syncthreads();   // h-stores drained to L2; exchange buffer reusable

        // ---- domain barrier (64 blocks of this XCD), counter at MALL
        unsigned* c = cnt + (((unsigned)t * 8u + (unsigned)domain) << 4);
        if (tid == 0) ag_add(c);

        // prefetch next step's one-hot projections during the wait
        if (w < 2) {
            const int tn = (t + 1 < SEQT) ? t + 1 : t;
            i32x4 idx = *(const i32x4*)(xT + tn * BATCH + r0 + w * 16 + (lHi << 2));
#pragma unroll
            for (int r = 0; r < 4; ++r) {
                xw0[r] = Wxg[(size_t)idx[r] * HID + hu];
                xw1[r] = Wxi[(size_t)idx[r] * HID + hu];
                xw2[r] = Wxf[(size_t)idx[r] * HID + hu];
                xw3[r] = Wxo[(size_t)idx[r] * HID + hu];
            }
        }

        if (tid == 0 && !dead) {
            if (!wait_ge(c, 64u, abortf, (1u << 17))) { dead = true; *bailp = 1; }
        }
        __syncthreads();
        // no fence: next step's sc0 loads hit the (coherent) shared L2 directly
    }
}

// out[256][128] = h_512 @ W_hp + b_p  (h_512 in hbuf[0]; dispatch-boundary
// release/acquire makes the L2-dirty h visible to this kernel)
__global__ void __launch_bounds__(256, 1) proj_kernel(
    const unsigned short* __restrict__ h, const float* __restrict__ Whp,
    const float* __restrict__ bp, float* __restrict__ out)
{
    __shared__ float red[4][256];
    const int tid  = threadIdx.x;
    const int n    = tid & 127;
    const int half = tid >> 7;
    const int b0   = blockIdx.x * 4;
    float s0 = 0.f, s1 = 0.f, s2 = 0.f, s3 = 0.f;
    for (int k = half * 512; k < half * 512 + 512; ++k) {
        float wv = Whp[(size_t)k * NCLS + n];
        s0 += bf2f(h[(size_t)(b0 + 0) * HID + k]) * wv;
        s1 += bf2f(h[(size_t)(b0 + 1) * HID + k]) * wv;
        s2 += bf2f(h[(size_t)(b0 + 2) * HID + k]) * wv;
        s3 += bf2f(h[(size_t)(b0 + 3) * HID + k]) * wv;
    }
    red[0][tid] = s0; red[1][tid] = s1; red[2][tid] = s2; red[3][tid] = s3;
    __syncthreads();
    if (tid < 128) {
#pragma unroll
        for (int j = 0; j < 4; ++j)
            out[(size_t)(b0 + j) * NCLS + tid] = red[j][tid] + red[j][tid + 128] + bp[tid];
    }
}

extern "C" void kernel_launch(void* const* d_in, const int* in_sizes, int n_in,
                              void* d_out, int out_size, void* d_ws, size_t ws_size,
                              hipStream_t stream) {
    const int*   x   = (const int*)  d_in[0];
    const float* Wxg = (const float*)d_in[1];
    const float* Whg = (const float*)d_in[2];
    const float* b_g = (const float*)d_in[3];
    const float* Wxi = (const float*)d_in[4];
    const float* Whi = (const float*)d_in[5];
    const float* b_i = (const float*)d_in[6];
    const float* Wxf = (const float*)d_in[7];
    const float* Whf = (const float*)d_in[8];
    const float* b_f = (const float*)d_in[9];
    const float* Wxo = (const float*)d_in[10];
    const float* Who = (const float*)d_in[11];
    const float* b_o = (const float*)d_in[12];
    const float* Whp = (const float*)d_in[13];
    const float* b_p = (const float*)d_in[14];
    float* out = (float*)d_out;

    char* ws = (char*)d_ws;
    unsigned short* hbuf = (unsigned short*)ws;                           // 2*256*1024 bf16 = 1 MB
    int*            xT   = (int*)(ws + (1 << 20));                        // 512 KB
    unsigned int*   cnt  = (unsigned int*)(ws + (1 << 20) + (512*1024));  // 512*8 counters, 64B-padded = 256 KB
    unsigned int*   misc = cnt + 512 * 8 * 16;                            // ticket[8], rz1, rz2, abortf

    // re-zero barrier state per call (capture-safe; re-runs on every replay).
    // hbuf is NOT memset: blocks self-zero h_0 through their own L2 path.
    hipMemsetAsync(cnt, 0, (size_t)(512 * 8 * 16 + 64) * sizeof(unsigned int), stream);

    xtrans_kernel<<<256, 256, 0, stream>>>(x, xT);

    const int ldsBytes = 65536 + 12288 + 64;   // B1 + exchange + bail/bcast (<=80KB => 2 blocks/CU)
    (void)hipFuncSetAttribute((const void*)lstm_pers,
                              hipFuncAttributeMaxDynamicSharedMemorySize, ldsBytes);
    lstm_pers<<<512, 256, ldsBytes, stream>>>(xT, Wxg, Whg, b_g, Wxi, Whi, b_i,
                                              Wxf, Whf, b_f, Wxo, Who, b_o, hbuf, cnt, misc);

    proj_kernel<<<64, 256, 0, stream>>>(hbuf, Whp, b_p, out);
}